// Round 5
// baseline (162.076 us; speedup 1.0000x reference)
//
#include <hip/hip_runtime.h>
#include <stdint.h>

#define AS1 __attribute__((address_space(1)))
#define AS3 __attribute__((address_space(3)))

typedef float f32x4 __attribute__((ext_vector_type(4)));
typedef __bf16 bf16x8 __attribute__((ext_vector_type(8)));

// fp32 -> bf16, round-to-nearest-even (inputs are finite; no NaN handling needed)
__device__ __forceinline__ unsigned short f2bf(float f) {
    uint32_t x = __float_as_uint(f);
    x += 0x7FFFu + ((x >> 16) & 1u);
    return (unsigned short)(x >> 16);
}

__device__ __forceinline__ void gload_lds16(const void* g, void* l) {
    __builtin_amdgcn_global_load_lds((const AS1 void*)g, (AS3 void*)l, 16, 0, 0);
}

// ---------------------------------------------------------------------------
// Kernel 0: WT[n][f] = bf16(W[f][n]).  W is [256][256] fp32 row-major.
// ---------------------------------------------------------------------------
__global__ __launch_bounds__(256) void wt_kernel(const float* __restrict__ W,
                                                 unsigned short* __restrict__ WT) {
    __shared__ float tile[32][33];
    const int bf = blockIdx.x & 7;   // f-tile
    const int bn = blockIdx.x >> 3;  // n-tile
    const int t = threadIdx.x;
    const int c = t & 31, r = t >> 5;  // r in 0..7
#pragma unroll
    for (int i = 0; i < 4; ++i)
        tile[r + i * 8][c] = W[(bf * 32 + r + i * 8) * 256 + bn * 32 + c];
    __syncthreads();
#pragma unroll
    for (int i = 0; i < 4; ++i)
        WT[(bn * 32 + r + i * 8) * 256 + bf * 32 + c] = f2bf(tile[c][r + i * 8]);
}

// ---------------------------------------------------------------------------
// gemm1 (unchanged, verified): D[m][n] = sum_k A[m][k]*B[n][k], B bf16 staged
// via global_load_lds, A fp32 reg-staged+cvt. MODE 1 only here: bf16
// transposed store Out[n][m] (ld 8192).  Tile BM=32,BN=256,BK=64.
// ---------------------------------------------------------------------------
template <int LDA, int LDB, int KSTEPS>
__global__ __launch_bounds__(256) void gemm1_kernel(const float* __restrict__ A,
                                                    const unsigned short* __restrict__ B,
                                                    unsigned short* __restrict__ dkT) {
    __shared__ unsigned short Alds[32 * 64];
    __shared__ unsigned short Blds[256 * 64];

    const int t = threadIdx.x;
    const int w = t >> 6;
    const int l = t & 63;
    const int m0 = blockIdx.x * 32;

    const int ar = t >> 3;
    const int kq = t & 7;
    const float* gA = A + (size_t)(m0 + ar) * LDA + kq * 4;
    char* aw0 = (char*)Alds + ((ar * 128 + kq * 8) ^ ((ar & 7) << 4));
    char* aw1 = (char*)Alds + ((ar * 128 + 64 + kq * 8) ^ ((ar & 7) << 4));

    const int nr_base = w * 64 + (l >> 3);
    const int c16 = l & 7;

    f32x4 acc[2][4];
#pragma unroll
    for (int i = 0; i < 2; ++i)
#pragma unroll
        for (int j = 0; j < 4; ++j) acc[i][j] = (f32x4){0.f, 0.f, 0.f, 0.f};

    for (int step = 0; step < KSTEPS; ++step) {
        const int k0 = step * 64;
        __syncthreads();
#pragma unroll
        for (int i = 0; i < 8; ++i) {
            const int nr = nr_base + i * 8;
            const unsigned short* src =
                B + (size_t)nr * LDB + k0 + ((c16 ^ (nr & 7)) << 3);
            gload_lds16(src, (char*)Blds + (w * 512 + i * 64) * 16);
        }
        const f32x4 v0 = *(const f32x4*)(gA + k0);
        const f32x4 v1 = *(const f32x4*)(gA + k0 + 32);
        uint32_t p0 = (uint32_t)f2bf(v0.x) | ((uint32_t)f2bf(v0.y) << 16);
        uint32_t p1 = (uint32_t)f2bf(v0.z) | ((uint32_t)f2bf(v0.w) << 16);
        uint32_t p2 = (uint32_t)f2bf(v1.x) | ((uint32_t)f2bf(v1.y) << 16);
        uint32_t p3 = (uint32_t)f2bf(v1.z) | ((uint32_t)f2bf(v1.w) << 16);
        ((uint32_t*)aw0)[0] = p0;
        ((uint32_t*)aw0)[1] = p1;
        ((uint32_t*)aw1)[0] = p2;
        ((uint32_t*)aw1)[1] = p3;
        __syncthreads();
#pragma unroll
        for (int kh = 0; kh < 2; ++kh) {
            const int koffb = kh * 64 + ((l >> 4) << 4);
            bf16x8 af[2], bv[4];
#pragma unroll
            for (int im = 0; im < 2; ++im) {
                const int r = im * 16 + (l & 15);
                af[im] = *(const bf16x8*)((const char*)Alds +
                                          ((r * 128 + koffb) ^ ((r & 7) << 4)));
            }
#pragma unroll
            for (int jn = 0; jn < 4; ++jn) {
                const int n = w * 64 + jn * 16 + (l & 15);
                bv[jn] = *(const bf16x8*)((const char*)Blds +
                                          ((n * 128 + koffb) ^ ((n & 7) << 4)));
            }
#pragma unroll
            for (int im = 0; im < 2; ++im)
#pragma unroll
                for (int jn = 0; jn < 4; ++jn)
                    acc[im][jn] = __builtin_amdgcn_mfma_f32_16x16x32_bf16(
                        af[im], bv[jn], acc[im][jn], 0, 0, 0);
        }
    }

    // bf16 transposed store: dkT[n][m]
#pragma unroll
    for (int im = 0; im < 2; ++im) {
        const int mb = m0 + im * 16 + ((l >> 4) << 2);
#pragma unroll
        for (int jn = 0; jn < 4; ++jn) {
            const int n = w * 64 + jn * 16 + (l & 15);
            const uint32_t lo = (uint32_t)f2bf(acc[im][jn][0]) |
                                ((uint32_t)f2bf(acc[im][jn][1]) << 16);
            const uint32_t hi = (uint32_t)f2bf(acc[im][jn][2]) |
                                ((uint32_t)f2bf(acc[im][jn][3]) << 16);
            uint32_t* dst = (uint32_t*)&dkT[(size_t)n * 8192 + mb];
            dst[0] = lo;
            dst[1] = hi;
        }
    }
}

// ---------------------------------------------------------------------------
// gemm2: out = adj @ dk.  A (adj fp32) staged raw via global_load_lds into an
// 8 KB LDS tile (swizzled source, linear dest), cvt at fragment read.
// B (dkT bf16, 4 MB, L2-resident) is loaded per-lane DIRECTLY from global to
// registers — no LDS staging, no bank conflicts, barrier protects only A.
// Tile BM=32, BN=256, BK=64; 4 waves, wave tile 32x64.
// KSPLIT blocks per M-tile; ks==0 -> Out0, ks>0 -> partials in Pws.
// ---------------------------------------------------------------------------
template <int KSTEPS, int KSPLIT>
__global__ __launch_bounds__(256, 4) void gemm2_kernel(const float* __restrict__ A,
                                                       const unsigned short* __restrict__ B,
                                                       float* __restrict__ Out0,
                                                       float* __restrict__ Pws) {
    __shared__ float Afp[32 * 64];  // 8 KB fp32 (16B chunks XOR-swizzled per row)

    const int t = threadIdx.x;
    const int w = t >> 6;
    const int l = t & 63;
    const int mtile = blockIdx.x / KSPLIT;
    const int ks = blockIdx.x % KSPLIT;
    const int m0 = mtile * 32;
    const int kbase = ks * KSTEPS * 64;

    // A staging map (issue j=0,1): row = j*16 + w*4 + (l>>4), col-chunk = l&15,
    // source chunk XOR-swizzled so the linear LDS dest lands swizzled.
    const int rowj0 = w * 4 + (l >> 4);
    const int ca = l & 15;
    const float* gAs = A + (size_t)(m0 + rowj0) * 8192 + kbase +
                       ((ca ^ (rowj0 & 7)) << 2);
    char* ldsA0 = (char*)Afp + w * 1024;
    char* ldsA1 = ldsA0 + 4096;

    // B fragment row pointers: n = w*64 + jn*16 + (l&15); k-lane = (l>>4)*8
    const unsigned short* rp[4];
#pragma unroll
    for (int jn = 0; jn < 4; ++jn)
        rp[jn] = B + (size_t)(w * 64 + jn * 16 + (l & 15)) * 8192 + kbase +
                 ((l >> 4) << 3);

    f32x4 acc[2][4];
#pragma unroll
    for (int i = 0; i < 2; ++i)
#pragma unroll
        for (int j = 0; j < 4; ++j) acc[i][j] = (f32x4){0.f, 0.f, 0.f, 0.f};

    for (int step = 0; step < KSTEPS; ++step) {
        const int k0 = step * 64;
        __syncthreads();  // previous compute done -> A LDS reusable
        // ---- A tile: [32 m][64 k] fp32 via global_load_lds (raw)
        gload_lds16(gAs + k0, ldsA0);
        gload_lds16(gAs + (size_t)16 * 8192 + k0, ldsA1);
        // ---- B fragments: direct global->reg (L2-resident panel)
        bf16x8 bfr[2][4];
#pragma unroll
        for (int kh = 0; kh < 2; ++kh)
#pragma unroll
            for (int jn = 0; jn < 4; ++jn)
                bfr[kh][jn] = *(const bf16x8*)(rp[jn] + k0 + kh * 32);
        __syncthreads();  // vmcnt(0) drain: A in LDS, B in regs
        // ---- compute: 2 k-halves x (2 x 4) fragments
#pragma unroll
        for (int kh = 0; kh < 2; ++kh) {
            bf16x8 af[2];
#pragma unroll
            for (int im = 0; im < 2; ++im) {
                const int r = im * 16 + (l & 15);
                const int cb = kh * 8 + ((l >> 4) << 1);
                const char* base = (const char*)Afp + r * 256;
                const int sw = (r & 7) << 4;
                const f32x4 u0 = *(const f32x4*)(base + ((cb << 4) ^ sw));
                const f32x4 u1 = *(const f32x4*)(base + (((cb + 1) << 4) ^ sw));
                bf16x8 a;
                a[0] = (__bf16)u0.x; a[1] = (__bf16)u0.y;
                a[2] = (__bf16)u0.z; a[3] = (__bf16)u0.w;
                a[4] = (__bf16)u1.x; a[5] = (__bf16)u1.y;
                a[6] = (__bf16)u1.z; a[7] = (__bf16)u1.w;
                af[im] = a;
            }
#pragma unroll
            for (int im = 0; im < 2; ++im)
#pragma unroll
                for (int jn = 0; jn < 4; ++jn)
                    acc[im][jn] = __builtin_amdgcn_mfma_f32_16x16x32_bf16(
                        af[im], bfr[kh][jn], acc[im][jn], 0, 0, 0);
        }
    }

    // ---- epilogue.  C/D frag: col = l&15, row = (l>>4)*4 + reg  [m89]
    float* Og = (KSPLIT == 1 || ks == 0) ? Out0
                                         : (Pws + (size_t)(ks - 1) * (8192 * 256));
#pragma unroll
    for (int im = 0; im < 2; ++im) {
        const int row0 = m0 + im * 16 + ((l >> 4) << 2);
#pragma unroll
        for (int jn = 0; jn < 4; ++jn) {
            const int col = w * 64 + jn * 16 + (l & 15);
#pragma unroll
            for (int r = 0; r < 4; ++r) {
                float v = acc[im][jn][r];
                if (KSPLIT == 1) v = v > 0.f ? v : 0.f;
                Og[(size_t)(row0 + r) * 256 + col] = v;
            }
        }
    }
}

// ---------------------------------------------------------------------------
// out = relu(out + sum_{s} P[s])   over 8192*256 fp32, vectorized f32x4.
// ---------------------------------------------------------------------------
template <int S>
__global__ __launch_bounds__(256) void reduce_relu_kernel(float* __restrict__ out,
                                                          const float* __restrict__ P) {
    const int i = blockIdx.x * 256 + threadIdx.x;  // f32x4 index, 524288 total
    f32x4 v = ((const f32x4*)out)[i];
#pragma unroll
    for (int s = 0; s < S - 1; ++s) {
        const f32x4 p = ((const f32x4*)P)[(size_t)s * 524288 + i];
        v.x += p.x; v.y += p.y; v.z += p.z; v.w += p.w;
    }
    v.x = v.x > 0.f ? v.x : 0.f;
    v.y = v.y > 0.f ? v.y : 0.f;
    v.z = v.z > 0.f ? v.z : 0.f;
    v.w = v.w > 0.f ? v.w : 0.f;
    ((f32x4*)out)[i] = v;
}

// ---------------------------------------------------------------------------
extern "C" void kernel_launch(void* const* d_in, const int* in_sizes, int n_in,
                              void* d_out, int out_size, void* d_ws, size_t ws_size,
                              hipStream_t stream) {
    const float* data = (const float*)d_in[0];  // [1,8192,256] fp32
    const float* adj = (const float*)d_in[1];   // [1,8192,8192] fp32
    const float* Wk = (const float*)d_in[2];    // [256,256] fp32
    float* out = (float*)d_out;                 // [1,8192,256] fp32

    unsigned short* WT = (unsigned short*)d_ws;                     // 128 KB bf16 W^T
    unsigned short* dkT = (unsigned short*)((char*)d_ws + 131072);  // 4 MB bf16 (data@W)^T
    float* P = (float*)((char*)d_ws + 131072 + 4194304);            // split-K partials

    const size_t base_need = 131072 + 4194304;
    const size_t part_bytes = (size_t)8192 * 256 * 4;  // 8 MB per extra split

    // 1) W^T in bf16
    wt_kernel<<<64, 256, 0, stream>>>(Wk, WT);
    // 2) dkT[n][m] = (data @ W)^T   : M=8192, N=256, K=256
    gemm1_kernel<256, 256, 4><<<256, 256, 0, stream>>>(data, WT, dkT);
    // 3) out = relu(adj @ dk)       : M=8192, N=256, K=8192
    //    split-K=4 -> grid 1024 -> 4 blocks/CU resident; B direct from L2.
    if (ws_size >= base_need + 3 * part_bytes) {
        gemm2_kernel<32, 4><<<1024, 256, 0, stream>>>(adj, dkT, out, P);
        reduce_relu_kernel<4><<<2048, 256, 0, stream>>>(out, P);
    } else if (ws_size >= base_need + part_bytes) {
        gemm2_kernel<64, 2><<<512, 256, 0, stream>>>(adj, dkT, out, P);
        reduce_relu_kernel<2><<<2048, 256, 0, stream>>>(out, P);
    } else {
        gemm2_kernel<128, 1><<<256, 256, 0, stream>>>(adj, dkT, out, nullptr);
    }
}

// Round 6
// 128.750 us; speedup vs baseline: 1.2588x; 1.2588x over previous
//
#include <hip/hip_runtime.h>
#include <stdint.h>

#define AS1 __attribute__((address_space(1)))
#define AS3 __attribute__((address_space(3)))

typedef float f32x4 __attribute__((ext_vector_type(4)));
typedef __bf16 bf16x8 __attribute__((ext_vector_type(8)));

// fp32 -> bf16, round-to-nearest-even
__device__ __forceinline__ unsigned short f2bf(float f) {
    uint32_t x = __float_as_uint(f);
    x += 0x7FFFu + ((x >> 16) & 1u);
    return (unsigned short)(x >> 16);
}

__device__ __forceinline__ void gload_lds16(const void* g, void* l) {
    __builtin_amdgcn_global_load_lds((const AS1 void*)g, (AS3 void*)l, 16, 0, 0);
}

// ---------------------------------------------------------------------------
// Kernel 0: WT[n][f] = bf16(W[f][n]).  W is [256][256] fp32 row-major.
// ---------------------------------------------------------------------------
__global__ __launch_bounds__(256) void wt_kernel(const float* __restrict__ W,
                                                 unsigned short* __restrict__ WT) {
    __shared__ float tile[32][33];
    const int bf = blockIdx.x & 7;
    const int bn = blockIdx.x >> 3;
    const int t = threadIdx.x;
    const int c = t & 31, r = t >> 5;
#pragma unroll
    for (int i = 0; i < 4; ++i)
        tile[r + i * 8][c] = W[(bf * 32 + r + i * 8) * 256 + bn * 32 + c];
    __syncthreads();
#pragma unroll
    for (int i = 0; i < 4; ++i)
        WT[(bn * 32 + r + i * 8) * 256 + bf * 32 + c] = f2bf(tile[c][r + i * 8]);
}

// ---------------------------------------------------------------------------
// gemm1 (verified r1-r5): dkT[n][m] = bf16( sum_k data[m][k]*WT[n][k] ).
// Tile BM=32, BN=256, BK=64; 4 waves.
// ---------------------------------------------------------------------------
template <int LDA, int LDB, int KSTEPS>
__global__ __launch_bounds__(256) void gemm1_kernel(const float* __restrict__ A,
                                                    const unsigned short* __restrict__ B,
                                                    unsigned short* __restrict__ dkT) {
    __shared__ unsigned short Alds[32 * 64];
    __shared__ unsigned short Blds[256 * 64];

    const int t = threadIdx.x;
    const int w = t >> 6;
    const int l = t & 63;
    const int m0 = blockIdx.x * 32;

    const int ar = t >> 3;
    const int kq = t & 7;
    const float* gA = A + (size_t)(m0 + ar) * LDA + kq * 4;
    char* aw0 = (char*)Alds + ((ar * 128 + kq * 8) ^ ((ar & 7) << 4));
    char* aw1 = (char*)Alds + ((ar * 128 + 64 + kq * 8) ^ ((ar & 7) << 4));

    const int nr_base = w * 64 + (l >> 3);
    const int c16 = l & 7;

    f32x4 acc[2][4];
#pragma unroll
    for (int i = 0; i < 2; ++i)
#pragma unroll
        for (int j = 0; j < 4; ++j) acc[i][j] = (f32x4){0.f, 0.f, 0.f, 0.f};

    for (int step = 0; step < KSTEPS; ++step) {
        const int k0 = step * 64;
        __syncthreads();
#pragma unroll
        for (int i = 0; i < 8; ++i) {
            const int nr = nr_base + i * 8;
            const unsigned short* src =
                B + (size_t)nr * LDB + k0 + ((c16 ^ (nr & 7)) << 3);
            gload_lds16(src, (char*)Blds + (w * 512 + i * 64) * 16);
        }
        const f32x4 v0 = *(const f32x4*)(gA + k0);
        const f32x4 v1 = *(const f32x4*)(gA + k0 + 32);
        uint32_t p0 = (uint32_t)f2bf(v0.x) | ((uint32_t)f2bf(v0.y) << 16);
        uint32_t p1 = (uint32_t)f2bf(v0.z) | ((uint32_t)f2bf(v0.w) << 16);
        uint32_t p2 = (uint32_t)f2bf(v1.x) | ((uint32_t)f2bf(v1.y) << 16);
        uint32_t p3 = (uint32_t)f2bf(v1.z) | ((uint32_t)f2bf(v1.w) << 16);
        ((uint32_t*)aw0)[0] = p0;
        ((uint32_t*)aw0)[1] = p1;
        ((uint32_t*)aw1)[0] = p2;
        ((uint32_t*)aw1)[1] = p3;
        __syncthreads();
#pragma unroll
        for (int kh = 0; kh < 2; ++kh) {
            const int koffb = kh * 64 + ((l >> 4) << 4);
            bf16x8 af[2], bv[4];
#pragma unroll
            for (int im = 0; im < 2; ++im) {
                const int r = im * 16 + (l & 15);
                af[im] = *(const bf16x8*)((const char*)Alds +
                                          ((r * 128 + koffb) ^ ((r & 7) << 4)));
            }
#pragma unroll
            for (int jn = 0; jn < 4; ++jn) {
                const int n = w * 64 + jn * 16 + (l & 15);
                bv[jn] = *(const bf16x8*)((const char*)Blds +
                                          ((n * 128 + koffb) ^ ((n & 7) << 4)));
            }
#pragma unroll
            for (int im = 0; im < 2; ++im)
#pragma unroll
                for (int jn = 0; jn < 4; ++jn)
                    acc[im][jn] = __builtin_amdgcn_mfma_f32_16x16x32_bf16(
                        af[im], bv[jn], acc[im][jn], 0, 0, 0);
        }
    }

#pragma unroll
    for (int im = 0; im < 2; ++im) {
        const int mb = m0 + im * 16 + ((l >> 4) << 2);
#pragma unroll
        for (int jn = 0; jn < 4; ++jn) {
            const int n = w * 64 + jn * 16 + (l & 15);
            const uint32_t lo = (uint32_t)f2bf(acc[im][jn][0]) |
                                ((uint32_t)f2bf(acc[im][jn][1]) << 16);
            const uint32_t hi = (uint32_t)f2bf(acc[im][jn][2]) |
                                ((uint32_t)f2bf(acc[im][jn][3]) << 16);
            uint32_t* dst = (uint32_t*)&dkT[(size_t)n * 8192 + mb];
            dst[0] = lo;
            dst[1] = hi;
        }
    }
}

// ---------------------------------------------------------------------------
// gemm2: out = adj @ dk.  BM=256, BN=256, BK=32, 512 threads = 8 waves (2x4),
// wave tile 128x64, double-buffered LDS (2-phase T3 pipeline, one barrier per
// step).  A (adj fp32) raw via global_load_lds, 8 chunks/row, XOR-swz c^(r&7).
// B (dkT bf16, [n][8192]) via global_load_lds, 4 chunks/row, XOR-swz
// c^((n>>1)&3).  Fragment/epilogue lane-mapping identical to gemm1 (verified).
// KSPLIT blocks per M-tile: ks==0 -> Out0, ks>0 -> Pws[(ks-1)].
// ---------------------------------------------------------------------------
template <int KSPLIT>
__global__ __launch_bounds__(512, 2) void gemm2_kernel(const float* __restrict__ A,
                                                       const unsigned short* __restrict__ B,
                                                       float* __restrict__ Out0,
                                                       float* __restrict__ Pws) {
    __shared__ float Afp[2][256 * 32];            // 2 x 32 KB
    __shared__ unsigned short Bls[2][256 * 32];   // 2 x 16 KB

    const int t = threadIdx.x;  // 0..511
    const int w = t >> 6;       // wave 0..7
    const int l = t & 63;
    const int wr = w >> 2;      // 0..1
    const int wc = w & 3;       // 0..3
    const int mtile = blockIdx.x / KSPLIT;
    const int ks = blockIdx.x % KSPLIT;
    const int m0 = mtile * 256;
    const int kbase = ks * (8192 / KSPLIT);
    constexpr int NT = (8192 / KSPLIT) / 32;

    // A staging: issue i covers chunks [i*512, i*512+512); thread t -> chunk
    // i*512+t; row r = i*64 + (t>>3); stored pos p' = t&7 holds logical chunk
    // p = (t&7) ^ (r&7); (r&7) == (t>>3)&7 for all i.
    const int ar0 = t >> 3;
    const int ap = (t & 7) ^ (ar0 & 7);
    const float* gA = A + (size_t)(m0 + ar0) * 8192 + kbase + ap * 4;
    // B staging: issue i covers chunks [i*512, +512); n = i*128 + (t>>2);
    // p = (t&3) ^ ((n>>1)&3); (n>>1)&3 == (t>>3)&3 for all i.
    const int bn0 = t >> 2;
    const int bp = (t & 3) ^ ((t >> 3) & 3);
    const unsigned short* gB = B + (size_t)bn0 * 8192 + kbase + bp * 8;

    f32x4 acc[8][4];
#pragma unroll
    for (int i = 0; i < 8; ++i)
#pragma unroll
        for (int j = 0; j < 4; ++j) acc[i][j] = (f32x4){0.f, 0.f, 0.f, 0.f};

    auto STAGE = [&](int buf, int k0) {
#pragma unroll
        for (int i = 0; i < 4; ++i)
            gload_lds16(gA + (size_t)i * 64 * 8192 + k0,
                        (char*)Afp[buf] + (i * 512 + w * 64) * 16);
#pragma unroll
        for (int i = 0; i < 2; ++i)
            gload_lds16(gB + (size_t)i * 128 * 8192 + k0,
                        (char*)Bls[buf] + (i * 512 + w * 64) * 16);
    };

    const int q = l >> 4;
    const int li = l & 15;

    STAGE(0, 0);
    __syncthreads();

    for (int st = 0; st < NT; ++st) {
        if (st + 1 < NT) STAGE((st + 1) & 1, (st + 1) * 32);
        const int buf = st & 1;
        // ---- B fragments: n-row, 16B at logical chunk q, stored q^((n>>1)&3)
        bf16x8 bv[4];
        const int sb = (li >> 1) & 3;
#pragma unroll
        for (int jn = 0; jn < 4; ++jn) {
            const int n = wc * 64 + jn * 16 + li;
            bv[jn] = *(const bf16x8*)((const char*)Bls[buf] + n * 64 +
                                      ((q ^ sb) << 4));
        }
        // ---- A fragments + MFMA
#pragma unroll
        for (int im = 0; im < 8; ++im) {
            const int r = wr * 128 + im * 16 + li;
            const char* rowb = (const char*)Afp[buf] + r * 128;
            const int e0 = ((2 * q) ^ (li & 7)) << 4;   // logical chunk 2q
            const f32x4 u0 = *(const f32x4*)(rowb + e0);
            const f32x4 u1 = *(const f32x4*)(rowb + (e0 ^ 16));  // 2q+1
            bf16x8 a;
            a[0] = (__bf16)u0.x; a[1] = (__bf16)u0.y;
            a[2] = (__bf16)u0.z; a[3] = (__bf16)u0.w;
            a[4] = (__bf16)u1.x; a[5] = (__bf16)u1.y;
            a[6] = (__bf16)u1.z; a[7] = (__bf16)u1.w;
#pragma unroll
            for (int jn = 0; jn < 4; ++jn)
                acc[im][jn] = __builtin_amdgcn_mfma_f32_16x16x32_bf16(
                    a, bv[jn], acc[im][jn], 0, 0, 0);
        }
        __syncthreads();  // drains vmcnt(0): next buf staged; cur buf free
    }

    // ---- epilogue.  C/D frag: col = l&15, row = (l>>4)*4 + reg  [m89]
    float* Og = (KSPLIT == 1 || ks == 0) ? Out0
                                         : (Pws + (size_t)(ks - 1) * (8192 * 256));
#pragma unroll
    for (int im = 0; im < 8; ++im) {
        const int row0 = m0 + wr * 128 + im * 16 + ((l >> 4) << 2);
#pragma unroll
        for (int jn = 0; jn < 4; ++jn) {
            const int col = wc * 64 + jn * 16 + (l & 15);
#pragma unroll
            for (int r = 0; r < 4; ++r) {
                float v = acc[im][jn][r];
                if (KSPLIT == 1) v = v > 0.f ? v : 0.f;
                Og[(size_t)(row0 + r) * 256 + col] = v;
            }
        }
    }
}

// ---------------------------------------------------------------------------
// out = relu(out + sum_{s<S-1} P[s])   over 8192*256 fp32, f32x4 vectorized.
// ---------------------------------------------------------------------------
template <int S>
__global__ __launch_bounds__(256) void reduce_relu_kernel(float* __restrict__ out,
                                                          const float* __restrict__ P) {
    const int i = blockIdx.x * 256 + threadIdx.x;  // 524288 f32x4 total
    f32x4 v = ((const f32x4*)out)[i];
#pragma unroll
    for (int s = 0; s < S - 1; ++s) {
        const f32x4 p = ((const f32x4*)P)[(size_t)s * 524288 + i];
        v.x += p.x; v.y += p.y; v.z += p.z; v.w += p.w;
    }
    v.x = v.x > 0.f ? v.x : 0.f;
    v.y = v.y > 0.f ? v.y : 0.f;
    v.z = v.z > 0.f ? v.z : 0.f;
    v.w = v.w > 0.f ? v.w : 0.f;
    ((f32x4*)out)[i] = v;
}

// ---------------------------------------------------------------------------
extern "C" void kernel_launch(void* const* d_in, const int* in_sizes, int n_in,
                              void* d_out, int out_size, void* d_ws, size_t ws_size,
                              hipStream_t stream) {
    const float* data = (const float*)d_in[0];  // [1,8192,256] fp32
    const float* adj = (const float*)d_in[1];   // [1,8192,8192] fp32
    const float* Wk = (const float*)d_in[2];    // [256,256] fp32
    float* out = (float*)d_out;                 // [1,8192,256] fp32

    unsigned short* WT = (unsigned short*)d_ws;                     // 128 KB
    unsigned short* dkT = (unsigned short*)((char*)d_ws + 131072);  // 4 MB bf16
    float* P = (float*)((char*)d_ws + 131072 + 4194304);            // partials

    const size_t base_need = 131072 + 4194304;
    const size_t part_bytes = (size_t)8192 * 256 * 4;  // 8 MB per extra split

    // 1) W^T in bf16
    wt_kernel<<<64, 256, 0, stream>>>(Wk, WT);
    // 2) dkT[n][m] = (data @ W)^T   : M=8192, N=256, K=256
    gemm1_kernel<256, 256, 4><<<256, 256, 0, stream>>>(data, WT, dkT);
    // 3) out = relu(adj @ dk)       : M=8192, N=256, K=8192
    //    BM=256 tile, KSPLIT=8 -> grid 256 = 1 block/CU, 2-phase dbuf.
    if (ws_size >= base_need + 7 * part_bytes) {
        gemm2_kernel<8><<<256, 512, 0, stream>>>(adj, dkT, out, P);
        reduce_relu_kernel<8><<<2048, 256, 0, stream>>>(out, P);
    } else if (ws_size >= base_need + part_bytes) {
        gemm2_kernel<2><<<64, 512, 0, stream>>>(adj, dkT, out, P);
        reduce_relu_kernel<2><<<2048, 256, 0, stream>>>(out, P);
    } else {
        gemm2_kernel<1><<<32, 512, 0, stream>>>(adj, dkT, out, nullptr);
    }
}

// Round 7
// 125.725 us; speedup vs baseline: 1.2891x; 1.0241x over previous
//
#include <hip/hip_runtime.h>
#include <stdint.h>

#define AS1 __attribute__((address_space(1)))
#define AS3 __attribute__((address_space(3)))

typedef float f32x4 __attribute__((ext_vector_type(4)));
typedef __bf16 bf16x8 __attribute__((ext_vector_type(8)));

// fp32 -> bf16, round-to-nearest-even
__device__ __forceinline__ unsigned short f2bf(float f) {
    uint32_t x = __float_as_uint(f);
    x += 0x7FFFu + ((x >> 16) & 1u);
    return (unsigned short)(x >> 16);
}

__device__ __forceinline__ void gload_lds16(const void* g, void* l) {
    __builtin_amdgcn_global_load_lds((const AS1 void*)g, (AS3 void*)l, 16, 0, 0);
}

// ---------------------------------------------------------------------------
// Kernel 0: WT[n][f] = bf16(W[f][n]).  W is [256][256] fp32 row-major.
// ---------------------------------------------------------------------------
__global__ __launch_bounds__(256) void wt_kernel(const float* __restrict__ W,
                                                 unsigned short* __restrict__ WT) {
    __shared__ float tile[32][33];
    const int bf = blockIdx.x & 7;
    const int bn = blockIdx.x >> 3;
    const int t = threadIdx.x;
    const int c = t & 31, r = t >> 5;
#pragma unroll
    for (int i = 0; i < 4; ++i)
        tile[r + i * 8][c] = W[(bf * 32 + r + i * 8) * 256 + bn * 32 + c];
    __syncthreads();
#pragma unroll
    for (int i = 0; i < 4; ++i)
        WT[(bn * 32 + r + i * 8) * 256 + bf * 32 + c] = f2bf(tile[c][r + i * 8]);
}

// ---------------------------------------------------------------------------
// gemm1 (verified r1-r6): dkT[n][m] = bf16( sum_k data[m][k]*WT[n][k] ).
// Tile BM=32, BN=256, BK=64; 4 waves.
// ---------------------------------------------------------------------------
template <int LDA, int LDB, int KSTEPS>
__global__ __launch_bounds__(256) void gemm1_kernel(const float* __restrict__ A,
                                                    const unsigned short* __restrict__ B,
                                                    unsigned short* __restrict__ dkT) {
    __shared__ unsigned short Alds[32 * 64];
    __shared__ unsigned short Blds[256 * 64];

    const int t = threadIdx.x;
    const int w = t >> 6;
    const int l = t & 63;
    const int m0 = blockIdx.x * 32;

    const int ar = t >> 3;
    const int kq = t & 7;
    const float* gA = A + (size_t)(m0 + ar) * LDA + kq * 4;
    char* aw0 = (char*)Alds + ((ar * 128 + kq * 8) ^ ((ar & 7) << 4));
    char* aw1 = (char*)Alds + ((ar * 128 + 64 + kq * 8) ^ ((ar & 7) << 4));

    const int nr_base = w * 64 + (l >> 3);
    const int c16 = l & 7;

    f32x4 acc[2][4];
#pragma unroll
    for (int i = 0; i < 2; ++i)
#pragma unroll
        for (int j = 0; j < 4; ++j) acc[i][j] = (f32x4){0.f, 0.f, 0.f, 0.f};

    for (int step = 0; step < KSTEPS; ++step) {
        const int k0 = step * 64;
        __syncthreads();
#pragma unroll
        for (int i = 0; i < 8; ++i) {
            const int nr = nr_base + i * 8;
            const unsigned short* src =
                B + (size_t)nr * LDB + k0 + ((c16 ^ (nr & 7)) << 3);
            gload_lds16(src, (char*)Blds + (w * 512 + i * 64) * 16);
        }
        const f32x4 v0 = *(const f32x4*)(gA + k0);
        const f32x4 v1 = *(const f32x4*)(gA + k0 + 32);
        uint32_t p0 = (uint32_t)f2bf(v0.x) | ((uint32_t)f2bf(v0.y) << 16);
        uint32_t p1 = (uint32_t)f2bf(v0.z) | ((uint32_t)f2bf(v0.w) << 16);
        uint32_t p2 = (uint32_t)f2bf(v1.x) | ((uint32_t)f2bf(v1.y) << 16);
        uint32_t p3 = (uint32_t)f2bf(v1.z) | ((uint32_t)f2bf(v1.w) << 16);
        ((uint32_t*)aw0)[0] = p0;
        ((uint32_t*)aw0)[1] = p1;
        ((uint32_t*)aw1)[0] = p2;
        ((uint32_t*)aw1)[1] = p3;
        __syncthreads();
#pragma unroll
        for (int kh = 0; kh < 2; ++kh) {
            const int koffb = kh * 64 + ((l >> 4) << 4);
            bf16x8 af[2], bv[4];
#pragma unroll
            for (int im = 0; im < 2; ++im) {
                const int r = im * 16 + (l & 15);
                af[im] = *(const bf16x8*)((const char*)Alds +
                                          ((r * 128 + koffb) ^ ((r & 7) << 4)));
            }
#pragma unroll
            for (int jn = 0; jn < 4; ++jn) {
                const int n = w * 64 + jn * 16 + (l & 15);
                bv[jn] = *(const bf16x8*)((const char*)Blds +
                                          ((n * 128 + koffb) ^ ((n & 7) << 4)));
            }
#pragma unroll
            for (int im = 0; im < 2; ++im)
#pragma unroll
                for (int jn = 0; jn < 4; ++jn)
                    acc[im][jn] = __builtin_amdgcn_mfma_f32_16x16x32_bf16(
                        af[im], bv[jn], acc[im][jn], 0, 0, 0);
        }
    }

#pragma unroll
    for (int im = 0; im < 2; ++im) {
        const int mb = m0 + im * 16 + ((l >> 4) << 2);
#pragma unroll
        for (int jn = 0; jn < 4; ++jn) {
            const int n = w * 64 + jn * 16 + (l & 15);
            const uint32_t lo = (uint32_t)f2bf(acc[im][jn][0]) |
                                ((uint32_t)f2bf(acc[im][jn][1]) << 16);
            const uint32_t hi = (uint32_t)f2bf(acc[im][jn][2]) |
                                ((uint32_t)f2bf(acc[im][jn][3]) << 16);
            uint32_t* dst = (uint32_t*)&dkT[(size_t)n * 8192 + mb];
            dst[0] = lo;
            dst[1] = hi;
        }
    }
}

// ---------------------------------------------------------------------------
// gemm2: out = adj @ dk.  BM=256, BN=256, BK=32, 512 threads = 8 waves (2x4),
// wave tile 128x64.  Double-buffered LDS with COUNTED vmcnt (T4): raw
// s_barrier + "s_waitcnt vmcnt(6)" keeps the next step's 6 global_load_lds
// in flight across the barrier (never drain to 0 in the main loop).
// A (adj fp32) raw via global_load_lds, 8 chunks/row, XOR-swz c^(r&7).
// B (dkT bf16) via global_load_lds, 4 chunks/row, XOR-swz c^((n>>1)&3).
// Fragment/epilogue lane-mapping identical to round-6 PASSING kernel.
// KSPLIT blocks per M-tile: ks==0 -> Out0, ks>0 -> Pws[(ks-1)].
// ---------------------------------------------------------------------------
template <int KSPLIT>
__global__ __launch_bounds__(512, 2) void gemm2_kernel(const float* __restrict__ A,
                                                       const unsigned short* __restrict__ B,
                                                       float* __restrict__ Out0,
                                                       float* __restrict__ Pws) {
    __shared__ float Afp[2][256 * 32];            // 2 x 32 KB
    __shared__ unsigned short Bls[2][256 * 32];   // 2 x 16 KB

    const int t = threadIdx.x;  // 0..511
    const int w = t >> 6;       // wave 0..7
    const int l = t & 63;
    const int wr = w >> 2;      // 0..1
    const int wc = w & 3;       // 0..3
    const int mtile = blockIdx.x / KSPLIT;
    const int ks = blockIdx.x % KSPLIT;
    const int m0 = mtile * 256;
    const int kbase = ks * (8192 / KSPLIT);
    constexpr int NT = (8192 / KSPLIT) / 32;

    // A staging: issue i covers chunks [i*512, i*512+512); thread t -> chunk
    // i*512+t; row r = i*64 + (t>>3); stored pos t&7 holds logical chunk
    // (t&7)^(r&7); (r&7) == (t>>3)&7 for all i.
    const int ar0 = t >> 3;
    const int ap = (t & 7) ^ (ar0 & 7);
    const float* gA = A + (size_t)(m0 + ar0) * 8192 + kbase + ap * 4;
    // B staging: issue i covers chunks [i*512, +512); n = i*128 + (t>>2);
    // stored pos t&3 holds logical chunk (t&3)^((n>>1)&3).
    const int bn0 = t >> 2;
    const int bp = (t & 3) ^ ((t >> 3) & 3);
    const unsigned short* gB = B + (size_t)bn0 * 8192 + kbase + bp * 8;

    f32x4 acc[8][4];
#pragma unroll
    for (int i = 0; i < 8; ++i)
#pragma unroll
        for (int j = 0; j < 4; ++j) acc[i][j] = (f32x4){0.f, 0.f, 0.f, 0.f};

    // 6 global_load_lds per thread per STAGE (4 A + 2 B)
    auto STAGE = [&](int buf, int k0) {
#pragma unroll
        for (int i = 0; i < 4; ++i)
            gload_lds16(gA + (size_t)i * 64 * 8192 + k0,
                        (char*)Afp[buf] + (i * 512 + w * 64) * 16);
#pragma unroll
        for (int i = 0; i < 2; ++i)
            gload_lds16(gB + (size_t)i * 128 * 8192 + k0,
                        (char*)Bls[buf] + (i * 512 + w * 64) * 16);
    };

    const int q = l >> 4;
    const int li = l & 15;

    STAGE(0, 0);
    if (NT > 1) STAGE(1, 32);

    for (int st = 0; st < NT; ++st) {
        const int buf = st & 1;
        // Wait only for the OLDEST buffer's 6 loads; keep the newer 6 in
        // flight across the barrier.  Final step drains everything.
        if (st + 1 < NT) {
            asm volatile("s_waitcnt vmcnt(6)" ::: "memory");
        } else {
            asm volatile("s_waitcnt vmcnt(0)" ::: "memory");
        }
        __builtin_amdgcn_s_barrier();
        __builtin_amdgcn_sched_barrier(0);

        // ---- B fragments: n-row, 16B at logical chunk q, stored q^((n>>1)&3)
        bf16x8 bv[4];
        const int sb = (li >> 1) & 3;
#pragma unroll
        for (int jn = 0; jn < 4; ++jn) {
            const int n = wc * 64 + jn * 16 + li;
            bv[jn] = *(const bf16x8*)((const char*)Bls[buf] + n * 64 +
                                      ((q ^ sb) << 4));
        }
        // ---- A fragments + MFMA
#pragma unroll
        for (int im = 0; im < 8; ++im) {
            const int r = wr * 128 + im * 16 + li;
            const char* rowb = (const char*)Afp[buf] + r * 128;
            const int e0 = ((2 * q) ^ (li & 7)) << 4;   // logical chunk 2q
            const f32x4 u0 = *(const f32x4*)(rowb + e0);
            const f32x4 u1 = *(const f32x4*)(rowb + (e0 ^ 16));  // 2q+1
            bf16x8 a;
            a[0] = (__bf16)u0.x; a[1] = (__bf16)u0.y;
            a[2] = (__bf16)u0.z; a[3] = (__bf16)u0.w;
            a[4] = (__bf16)u1.x; a[5] = (__bf16)u1.y;
            a[6] = (__bf16)u1.z; a[7] = (__bf16)u1.w;
#pragma unroll
            for (int jn = 0; jn < 4; ++jn)
                acc[im][jn] = __builtin_amdgcn_mfma_f32_16x16x32_bf16(
                    a, bv[jn], acc[im][jn], 0, 0, 0);
        }

        __builtin_amdgcn_s_barrier();  // all waves done reading buf
        if (st + 2 < NT) STAGE(buf, (st + 2) * 32);  // DMA into freed buf
    }

    // ---- epilogue.  C/D frag: col = l&15, row = (l>>4)*4 + reg  [m89]
    float* Og = (KSPLIT == 1 || ks == 0) ? Out0
                                         : (Pws + (size_t)(ks - 1) * (8192 * 256));
#pragma unroll
    for (int im = 0; im < 8; ++im) {
        const int row0 = m0 + wr * 128 + im * 16 + ((l >> 4) << 2);
#pragma unroll
        for (int jn = 0; jn < 4; ++jn) {
            const int col = wc * 64 + jn * 16 + (l & 15);
#pragma unroll
            for (int r = 0; r < 4; ++r) {
                float v = acc[im][jn][r];
                if (KSPLIT == 1) v = v > 0.f ? v : 0.f;
                Og[(size_t)(row0 + r) * 256 + col] = v;
            }
        }
    }
}

// ---------------------------------------------------------------------------
// out = relu(out + sum_{s<S-1} P[s])   over 8192*256 fp32, f32x4 vectorized.
// ---------------------------------------------------------------------------
template <int S>
__global__ __launch_bounds__(256) void reduce_relu_kernel(float* __restrict__ out,
                                                          const float* __restrict__ P) {
    const int i = blockIdx.x * 256 + threadIdx.x;  // 524288 f32x4 total
    f32x4 v = ((const f32x4*)out)[i];
#pragma unroll
    for (int s = 0; s < S - 1; ++s) {
        const f32x4 p = ((const f32x4*)P)[(size_t)s * 524288 + i];
        v.x += p.x; v.y += p.y; v.z += p.z; v.w += p.w;
    }
    v.x = v.x > 0.f ? v.x : 0.f;
    v.y = v.y > 0.f ? v.y : 0.f;
    v.z = v.z > 0.f ? v.z : 0.f;
    v.w = v.w > 0.f ? v.w : 0.f;
    ((f32x4*)out)[i] = v;
}

// ---------------------------------------------------------------------------
extern "C" void kernel_launch(void* const* d_in, const int* in_sizes, int n_in,
                              void* d_out, int out_size, void* d_ws, size_t ws_size,
                              hipStream_t stream) {
    const float* data = (const float*)d_in[0];  // [1,8192,256] fp32
    const float* adj = (const float*)d_in[1];   // [1,8192,8192] fp32
    const float* Wk = (const float*)d_in[2];    // [256,256] fp32
    float* out = (float*)d_out;                 // [1,8192,256] fp32

    unsigned short* WT = (unsigned short*)d_ws;                     // 128 KB
    unsigned short* dkT = (unsigned short*)((char*)d_ws + 131072);  // 4 MB bf16
    float* P = (float*)((char*)d_ws + 131072 + 4194304);            // partials

    const size_t base_need = 131072 + 4194304;
    const size_t part_bytes = (size_t)8192 * 256 * 4;  // 8 MB per extra split

    // 1) W^T in bf16
    wt_kernel<<<64, 256, 0, stream>>>(Wk, WT);
    // 2) dkT[n][m] = (data @ W)^T   : M=8192, N=256, K=256
    gemm1_kernel<256, 256, 4><<<256, 256, 0, stream>>>(data, WT, dkT);
    // 3) out = relu(adj @ dk)       : M=8192, N=256, K=8192
    //    BM=256, KSPLIT=8 -> grid 256 = 1 block/CU, counted-vmcnt pipeline.
    if (ws_size >= base_need + 7 * part_bytes) {
        gemm2_kernel<8><<<256, 512, 0, stream>>>(adj, dkT, out, P);
        reduce_relu_kernel<8><<<2048, 256, 0, stream>>>(out, P);
    } else if (ws_size >= base_need + part_bytes) {
        gemm2_kernel<2><<<64, 512, 0, stream>>>(adj, dkT, out, P);
        reduce_relu_kernel<2><<<2048, 256, 0, stream>>>(out, P);
    } else {
        gemm2_kernel<1><<<32, 512, 0, stream>>>(adj, dkT, out, nullptr);
    }
}

// Round 8
// 111.262 us; speedup vs baseline: 1.4567x; 1.1300x over previous
//
#include <hip/hip_runtime.h>
#include <stdint.h>

#define AS1 __attribute__((address_space(1)))
#define AS3 __attribute__((address_space(3)))

typedef float f32x4 __attribute__((ext_vector_type(4)));
typedef __bf16 bf16x8 __attribute__((ext_vector_type(8)));
typedef uint32_t u32x2 __attribute__((ext_vector_type(2)));

// fp32 -> bf16, round-to-nearest-even
__device__ __forceinline__ unsigned short f2bf(float f) {
    uint32_t x = __float_as_uint(f);
    x += 0x7FFFu + ((x >> 16) & 1u);
    return (unsigned short)(x >> 16);
}

__device__ __forceinline__ void gload_lds16(const void* g, void* l) {
    __builtin_amdgcn_global_load_lds((const AS1 void*)g, (AS3 void*)l, 16, 0, 0);
}

// ---------------------------------------------------------------------------
// Kernel 0: WT[n][f] = bf16(W[f][n]).  W is [256][256] fp32 row-major.
// ---------------------------------------------------------------------------
__global__ __launch_bounds__(256) void wt_kernel(const float* __restrict__ W,
                                                 unsigned short* __restrict__ WT) {
    __shared__ float tile[32][33];
    const int bf = blockIdx.x & 7;
    const int bn = blockIdx.x >> 3;
    const int t = threadIdx.x;
    const int c = t & 31, r = t >> 5;
#pragma unroll
    for (int i = 0; i < 4; ++i)
        tile[r + i * 8][c] = W[(bf * 32 + r + i * 8) * 256 + bn * 32 + c];
    __syncthreads();
#pragma unroll
    for (int i = 0; i < 4; ++i)
        WT[(bn * 32 + r + i * 8) * 256 + bf * 32 + c] = f2bf(tile[c][r + i * 8]);
}

// ---------------------------------------------------------------------------
// gemm1 (verified r1-r7): dkT[n][m] = bf16( sum_k data[m][k]*WT[n][k] ).
// Tile BM=32, BN=256, BK=64; 4 waves.
// ---------------------------------------------------------------------------
template <int LDA, int LDB, int KSTEPS>
__global__ __launch_bounds__(256) void gemm1_kernel(const float* __restrict__ A,
                                                    const unsigned short* __restrict__ B,
                                                    unsigned short* __restrict__ dkT) {
    __shared__ unsigned short Alds[32 * 64];
    __shared__ unsigned short Blds[256 * 64];

    const int t = threadIdx.x;
    const int w = t >> 6;
    const int l = t & 63;
    const int m0 = blockIdx.x * 32;

    const int ar = t >> 3;
    const int kq = t & 7;
    const float* gA = A + (size_t)(m0 + ar) * LDA + kq * 4;
    char* aw0 = (char*)Alds + ((ar * 128 + kq * 8) ^ ((ar & 7) << 4));
    char* aw1 = (char*)Alds + ((ar * 128 + 64 + kq * 8) ^ ((ar & 7) << 4));

    const int nr_base = w * 64 + (l >> 3);
    const int c16 = l & 7;

    f32x4 acc[2][4];
#pragma unroll
    for (int i = 0; i < 2; ++i)
#pragma unroll
        for (int j = 0; j < 4; ++j) acc[i][j] = (f32x4){0.f, 0.f, 0.f, 0.f};

    for (int step = 0; step < KSTEPS; ++step) {
        const int k0 = step * 64;
        __syncthreads();
#pragma unroll
        for (int i = 0; i < 8; ++i) {
            const int nr = nr_base + i * 8;
            const unsigned short* src =
                B + (size_t)nr * LDB + k0 + ((c16 ^ (nr & 7)) << 3);
            gload_lds16(src, (char*)Blds + (w * 512 + i * 64) * 16);
        }
        const f32x4 v0 = *(const f32x4*)(gA + k0);
        const f32x4 v1 = *(const f32x4*)(gA + k0 + 32);
        uint32_t p0 = (uint32_t)f2bf(v0.x) | ((uint32_t)f2bf(v0.y) << 16);
        uint32_t p1 = (uint32_t)f2bf(v0.z) | ((uint32_t)f2bf(v0.w) << 16);
        uint32_t p2 = (uint32_t)f2bf(v1.x) | ((uint32_t)f2bf(v1.y) << 16);
        uint32_t p3 = (uint32_t)f2bf(v1.z) | ((uint32_t)f2bf(v1.w) << 16);
        ((uint32_t*)aw0)[0] = p0;
        ((uint32_t*)aw0)[1] = p1;
        ((uint32_t*)aw1)[0] = p2;
        ((uint32_t*)aw1)[1] = p3;
        __syncthreads();
#pragma unroll
        for (int kh = 0; kh < 2; ++kh) {
            const int koffb = kh * 64 + ((l >> 4) << 4);
            bf16x8 af[2], bv[4];
#pragma unroll
            for (int im = 0; im < 2; ++im) {
                const int r = im * 16 + (l & 15);
                af[im] = *(const bf16x8*)((const char*)Alds +
                                          ((r * 128 + koffb) ^ ((r & 7) << 4)));
            }
#pragma unroll
            for (int jn = 0; jn < 4; ++jn) {
                const int n = w * 64 + jn * 16 + (l & 15);
                bv[jn] = *(const bf16x8*)((const char*)Blds +
                                          ((n * 128 + koffb) ^ ((n & 7) << 4)));
            }
#pragma unroll
            for (int im = 0; im < 2; ++im)
#pragma unroll
                for (int jn = 0; jn < 4; ++jn)
                    acc[im][jn] = __builtin_amdgcn_mfma_f32_16x16x32_bf16(
                        af[im], bv[jn], acc[im][jn], 0, 0, 0);
        }
    }

#pragma unroll
    for (int im = 0; im < 2; ++im) {
        const int mb = m0 + im * 16 + ((l >> 4) << 2);
#pragma unroll
        for (int jn = 0; jn < 4; ++jn) {
            const int n = w * 64 + jn * 16 + (l & 15);
            const uint32_t lo = (uint32_t)f2bf(acc[im][jn][0]) |
                                ((uint32_t)f2bf(acc[im][jn][1]) << 16);
            const uint32_t hi = (uint32_t)f2bf(acc[im][jn][2]) |
                                ((uint32_t)f2bf(acc[im][jn][3]) << 16);
            uint32_t* dst = (uint32_t*)&dkT[(size_t)n * 8192 + mb];
            dst[0] = lo;
            dst[1] = hi;
        }
    }
}

// ---------------------------------------------------------------------------
// gemm2: out = adj @ dk.  BM=64, BN=256, BK=64, 256 threads = 4 waves, wave
// tile 64x64 (acc[4][4] = 64 VGPR).  Single-buffered m97-style 2-barrier loop;
// latency hidden by 3 RESIDENT BLOCKS/CU (launch_bounds(256,3), LDS 40 KB).
// B (dkT bf16) staged via global_load_lds, XOR-swz source (verbatim gemm1).
// A (adj fp32): 4 rounds of coalesced f32x4 loads -> cvt -> swizzled
// ds_write_b64 into a 64x64 bf16 tile (rows 128 B, chunk XOR c^(r&7)).
// KSPLIT blocks per M-tile: ks==0 -> Out0, ks>0 -> Pws[(ks-1)].
// ---------------------------------------------------------------------------
template <int KSPLIT>
__global__ __launch_bounds__(256, 3) void gemm2_kernel(const float* __restrict__ A,
                                                       const unsigned short* __restrict__ B,
                                                       float* __restrict__ Out0,
                                                       float* __restrict__ Pws) {
    __shared__ unsigned short Alds[64 * 64];   // 8 KB bf16, swizzled rows
    __shared__ unsigned short Blds[256 * 64];  // 32 KB bf16, swizzled rows

    const int t = threadIdx.x;
    const int w = t >> 6;
    const int l = t & 63;
    const int mtile = blockIdx.x / KSPLIT;
    const int ks = blockIdx.x % KSPLIT;
    const int m0 = mtile * 64;
    const int kbase = ks * (8192 / KSPLIT);
    constexpr int KSTEPS = (8192 / KSPLIT) / 64;

    // ---- A staging map: round j covers rows [j*16, j*16+16).
    //      thread t -> row-in-round jr = t>>4, 16B-chunk jc = t&15 (fp32).
    //      Per row: 16 threads read 256 B contiguous (coalesced).
    const int jr = t >> 4;
    const int jc = t & 15;
    const float* gA = A + (size_t)(m0 + jr) * 8192 + kbase + jc * 4;

    // ---- B staging map (verbatim gemm1): per issue i, row nr, 8 threads/row
    const int nr_base = w * 64 + (l >> 3);
    const int c16 = l & 7;

    f32x4 acc[4][4];
#pragma unroll
    for (int i = 0; i < 4; ++i)
#pragma unroll
        for (int j = 0; j < 4; ++j) acc[i][j] = (f32x4){0.f, 0.f, 0.f, 0.f};

    const int q = l >> 4;
    const int li = l & 15;

    for (int step = 0; step < KSTEPS; ++step) {
        const int k0 = step * 64;
        __syncthreads();  // previous compute done -> LDS reusable
        // ---- B tile: [256 n][64 k] bf16 via global_load_lds (8 issues)
#pragma unroll
        for (int i = 0; i < 8; ++i) {
            const int nr = nr_base + i * 8;
            const unsigned short* src =
                B + (size_t)nr * 8192 + kbase + k0 + ((c16 ^ (nr & 7)) << 3);
            gload_lds16(src, (char*)Blds + (w * 512 + i * 64) * 16);
        }
        // ---- A tile: [64 m][64 k] fp32 -> bf16, 4 rounds of 16 rows
#pragma unroll
        for (int j = 0; j < 4; ++j) {
            const f32x4 v = *(const f32x4*)(gA + (size_t)j * 16 * 8192 + k0);
            const int r = j * 16 + jr;
            const int p = (jc >> 1) ^ (r & 7);
            u32x2 pk;
            pk[0] = (uint32_t)f2bf(v.x) | ((uint32_t)f2bf(v.y) << 16);
            pk[1] = (uint32_t)f2bf(v.z) | ((uint32_t)f2bf(v.w) << 16);
            *(u32x2*)((char*)Alds + r * 128 + p * 16 + (jc & 1) * 8) = pk;
        }
        __syncthreads();  // drains vmcnt(0)+lgkmcnt(0): tiles ready
        // ---- compute: 2 k-halves x (4 m x 4 n) fragments
#pragma unroll
        for (int kh = 0; kh < 2; ++kh) {
            const int koffb = kh * 64 + (q << 4);
            bf16x8 af[4], bv[4];
#pragma unroll
            for (int im = 0; im < 4; ++im) {
                const int r = im * 16 + li;
                af[im] = *(const bf16x8*)((const char*)Alds +
                                          ((r * 128 + koffb) ^ ((r & 7) << 4)));
            }
#pragma unroll
            for (int jn = 0; jn < 4; ++jn) {
                const int n = w * 64 + jn * 16 + li;
                bv[jn] = *(const bf16x8*)((const char*)Blds +
                                          ((n * 128 + koffb) ^ ((n & 7) << 4)));
            }
#pragma unroll
            for (int im = 0; im < 4; ++im)
#pragma unroll
                for (int jn = 0; jn < 4; ++jn)
                    acc[im][jn] = __builtin_amdgcn_mfma_f32_16x16x32_bf16(
                        af[im], bv[jn], acc[im][jn], 0, 0, 0);
        }
    }

    // ---- epilogue.  C/D frag: col = l&15, row = (l>>4)*4 + reg  [m89]
    float* Og = (KSPLIT == 1 || ks == 0) ? Out0
                                         : (Pws + (size_t)(ks - 1) * (8192 * 256));
#pragma unroll
    for (int im = 0; im < 4; ++im) {
        const int row0 = m0 + im * 16 + (q << 2);
#pragma unroll
        for (int jn = 0; jn < 4; ++jn) {
            const int col = w * 64 + jn * 16 + li;
#pragma unroll
            for (int r = 0; r < 4; ++r) {
                float v = acc[im][jn][r];
                if (KSPLIT == 1) v = v > 0.f ? v : 0.f;
                Og[(size_t)(row0 + r) * 256 + col] = v;
            }
        }
    }
}

// ---------------------------------------------------------------------------
// out = relu(out + sum_{s<S-1} P[s])   over 8192*256 fp32, f32x4 vectorized.
// ---------------------------------------------------------------------------
template <int S>
__global__ __launch_bounds__(256) void reduce_relu_kernel(float* __restrict__ out,
                                                          const float* __restrict__ P) {
    const int i = blockIdx.x * 256 + threadIdx.x;  // 524288 f32x4 total
    f32x4 v = ((const f32x4*)out)[i];
#pragma unroll
    for (int s = 0; s < S - 1; ++s) {
        const f32x4 p = ((const f32x4*)P)[(size_t)s * 524288 + i];
        v.x += p.x; v.y += p.y; v.z += p.z; v.w += p.w;
    }
    v.x = v.x > 0.f ? v.x : 0.f;
    v.y = v.y > 0.f ? v.y : 0.f;
    v.z = v.z > 0.f ? v.z : 0.f;
    v.w = v.w > 0.f ? v.w : 0.f;
    ((f32x4*)out)[i] = v;
}

// ---------------------------------------------------------------------------
extern "C" void kernel_launch(void* const* d_in, const int* in_sizes, int n_in,
                              void* d_out, int out_size, void* d_ws, size_t ws_size,
                              hipStream_t stream) {
    const float* data = (const float*)d_in[0];  // [1,8192,256] fp32
    const float* adj = (const float*)d_in[1];   // [1,8192,8192] fp32
    const float* Wk = (const float*)d_in[2];    // [256,256] fp32
    float* out = (float*)d_out;                 // [1,8192,256] fp32

    unsigned short* WT = (unsigned short*)d_ws;                     // 128 KB
    unsigned short* dkT = (unsigned short*)((char*)d_ws + 131072);  // 4 MB bf16
    float* P = (float*)((char*)d_ws + 131072 + 4194304);            // partials

    const size_t base_need = 131072 + 4194304;
    const size_t part_bytes = (size_t)8192 * 256 * 4;  // 8 MB per extra split

    // 1) W^T in bf16
    wt_kernel<<<64, 256, 0, stream>>>(Wk, WT);
    // 2) dkT[n][m] = (data @ W)^T   : M=8192, N=256, K=256
    gemm1_kernel<256, 256, 4><<<256, 256, 0, stream>>>(data, WT, dkT);
    // 3) out = relu(adj @ dk)       : M=8192, N=256, K=8192
    //    BM=64, KSPLIT=8 -> grid 1024, 3 blocks/CU resident (m97-style TLP).
    if (ws_size >= base_need + 7 * part_bytes) {
        gemm2_kernel<8><<<1024, 256, 0, stream>>>(adj, dkT, out, P);
        reduce_relu_kernel<8><<<2048, 256, 0, stream>>>(out, P);
    } else if (ws_size >= base_need + part_bytes) {
        gemm2_kernel<2><<<256, 256, 0, stream>>>(adj, dkT, out, P);
        reduce_relu_kernel<2><<<2048, 256, 0, stream>>>(out, P);
    } else {
        gemm2_kernel<1><<<128, 256, 0, stream>>>(adj, dkT, out, nullptr);
    }
}